// Round 1
// 313.029 us; speedup vs baseline: 1.0387x; 1.0387x over previous
//
#include <hip/hip_runtime.h>

typedef unsigned short u16;
typedef unsigned int u32;
typedef u16 u16x8 __attribute__((ext_vector_type(8)));
typedef __bf16 bf16x8 __attribute__((ext_vector_type(8)));
typedef float f32x4 __attribute__((ext_vector_type(4)));

__device__ __forceinline__ u16 f2bf(float f) {
  union { float f; unsigned u; } c; c.f = f;
  unsigned u = c.u;
  return (u16)((u + 0x7fff + ((u >> 16) & 1)) >> 16);
}
__device__ __forceinline__ u32 fbits(float f) {
  union { float f; u32 u; } c; c.f = f; return c.u;
}

// async global->LDS, 16B per lane. LDS dest must be wave-uniform base + lane*16.
__device__ __forceinline__ void lds16(const u16* g, u16* l) {
  __builtin_amdgcn_global_load_lds(
      (const __attribute__((address_space(1))) unsigned int*)g,
      (__attribute__((address_space(3))) unsigned int*)l, 16, 0, 0);
}

// SCALE = (1280//8)^-0.5, folded with log2(e); baked into Q-projection weights
#define CEXP (0.07905694150420949f * 1.4426950408889634f)

// ---------------------------------------------------------------------------
// combined prep: Wd cast | Wqkv^T (+CEXP on Q rows) | Wup^T | x -> bf16
// ---------------------------------------------------------------------------
#define PREP_W (1280 * 256 + 768 * 256 + 1280 * 256)   // 851968 weight elems

__global__ __launch_bounds__(256)
void prep_all(const float* __restrict__ Wd, const float* __restrict__ Wqkv,
              const float* __restrict__ Wup, const float* __restrict__ X,
              u16* __restrict__ WdC, u16* __restrict__ WqkvT,
              u16* __restrict__ WupT, u16* __restrict__ Xb, int n8) {
  int id = blockIdx.x * 256 + threadIdx.x;
  if (id < 1280 * 256) {                      // straight cast of Wd
    WdC[id] = f2bf(Wd[id]);
    return;
  }
  id -= 1280 * 256;
  if (id < 768 * 256) {                       // Wqkv^T, scale Q rows by CEXP
    int n = id >> 8, c = id & 255;
    float v = Wqkv[(size_t)c * 768 + n];
    if (n < 256) v *= CEXP;
    WqkvT[id] = f2bf(v);
    return;
  }
  id -= 768 * 256;
  if (id < 1280 * 256) {                      // Wup^T
    int n = id >> 8, c = id & 255;
    WupT[id] = f2bf(Wup[(size_t)c * 1280 + n]);
    return;
  }
  id -= 1280 * 256;
  if (id < n8) {                              // x -> bf16, 8 elems/thread
    const float4* src = (const float4*)(X + (size_t)id * 8);
    float4 lo = src[0], hi = src[1];
    u16x8 v;
    v[0]=f2bf(lo.x); v[1]=f2bf(lo.y); v[2]=f2bf(lo.z); v[3]=f2bf(lo.w);
    v[4]=f2bf(hi.x); v[5]=f2bf(hi.y); v[6]=f2bf(hi.z); v[7]=f2bf(hi.w);
    *(u16x8*)(Xb + (size_t)id * 8) = v;
  }
}

// ---------------------------------------------------------------------------
// GEMM: C[M,N] = A[M,K] * BT[N,K]^T (+bias). m97 structure: unpadded LDS,
// global_load_lds width=16. Kept for small/short-K GEMMs + AF32 fallback.
// 128x128 tile, 4 waves of 64x64, BK=64.
// ---------------------------------------------------------------------------
template <int AF32>
__global__ __launch_bounds__(256)
void gemm_bt(const void* __restrict__ Av,
             const u16* __restrict__ BT,
             u16* __restrict__ Cb, float* __restrict__ Cf,
             const float* __restrict__ bias,
             int M, int N, int K)
{
  __shared__ u16 As[128][64];
  __shared__ u16 Bs[128][64];
  const int tid  = threadIdx.x;
  const int wave = tid >> 6, lane = tid & 63;
  const int quad = lane >> 4, l16 = lane & 15;

  const int nb = N >> 7, mb = M >> 7;
  int band, nblk;
  if ((mb & 7) == 0) {
    int xcd = blockIdx.x & 7, slot = blockIdx.x >> 3;
    band = xcd + 8 * (slot / nb);
    nblk = slot % nb;
  } else {
    band = blockIdx.x / nb;
    nblk = blockIdx.x % nb;
  }
  const int m0 = band * 128, n0 = nblk * 128;
  const int wr = (wave >> 1) * 64, wc = (wave & 1) * 64;
  const u16*   A16 = (const u16*)Av;
  const float* A32 = (const float*)Av;

  f32x4 acc[4][4];
#pragma unroll
  for (int i = 0; i < 4; i++)
#pragma unroll
    for (int j = 0; j < 4; j++) acc[i][j] = f32x4{0.f, 0.f, 0.f, 0.f};

  for (int k0 = 0; k0 < K; k0 += 64) {
    if constexpr (AF32) {
#pragma unroll
      for (int it = 0; it < 4; it++) {
        int idx = tid + it * 256;
        int r = idx >> 3;
        int c = (idx & 7) << 3;
        const float* src = &A32[(size_t)(m0 + r) * K + k0 + c];
        float4 lo = *(const float4*)src;
        float4 hi = *(const float4*)(src + 4);
        u16x8 v;
        v[0]=f2bf(lo.x); v[1]=f2bf(lo.y); v[2]=f2bf(lo.z); v[3]=f2bf(lo.w);
        v[4]=f2bf(hi.x); v[5]=f2bf(hi.y); v[6]=f2bf(hi.z); v[7]=f2bf(hi.w);
        *(u16x8*)&As[r][c] = v;
      }
#pragma unroll
      for (int it = 0; it < 4; it++) {
        int r0 = wave * 32 + it * 8;
        lds16(&BT[(size_t)(n0 + r0 + (lane >> 3)) * K + k0 + ((lane & 7) << 3)],
              &Bs[r0][0] + lane * 8);
      }
    } else {
#pragma unroll
      for (int it = 0; it < 4; it++) {
        int r0 = wave * 32 + it * 8;
        lds16(&A16[(size_t)(m0 + r0 + (lane >> 3)) * K + k0 + ((lane & 7) << 3)],
              &As[r0][0] + lane * 8);
        lds16(&BT[(size_t)(n0 + r0 + (lane >> 3)) * K + k0 + ((lane & 7) << 3)],
              &Bs[r0][0] + lane * 8);
      }
    }
    __syncthreads();
#pragma unroll
    for (int ks = 0; ks < 64; ks += 32) {
      bf16x8 af[4], bfr[4];
#pragma unroll
      for (int i = 0; i < 4; i++)
        af[i] = *(const bf16x8*)&As[wr + i * 16 + l16][ks + quad * 8];
#pragma unroll
      for (int j = 0; j < 4; j++)
        bfr[j] = *(const bf16x8*)&Bs[wc + j * 16 + l16][ks + quad * 8];
#pragma unroll
      for (int i = 0; i < 4; i++)
#pragma unroll
        for (int j = 0; j < 4; j++)
          acc[i][j] = __builtin_amdgcn_mfma_f32_16x16x32_bf16(af[i], bfr[j], acc[i][j], 0, 0, 0);
    }
    __syncthreads();
  }

  // epilogue: C/D layout col=lane&15, row=quad*4+reg
#pragma unroll
  for (int i = 0; i < 4; i++) {
#pragma unroll
    for (int j = 0; j < 4; j++) {
      int col = n0 + wc + j * 16 + l16;
      float bv = bias ? bias[col] : 0.0f;
#pragma unroll
      for (int r = 0; r < 4; r++) {
        int row = m0 + wr + i * 16 + quad * 4 + r;
        float v = acc[i][j][r] + bv;
        if (Cf) Cf[(size_t)row * N + col] = v;
        else    Cb[(size_t)row * N + col] = f2bf(v);
      }
    }
  }
}

// ---------------------------------------------------------------------------
// Big-GEMM: 256x256 tile, 512 threads (8 waves 2Mx4N, wave tile 128x64),
// BK=32, 4 LDS buffers (128 KiB), counted-vmcnt pipeline (T3+T4):
//   iter t: issue stage of tile t+3 -> buf (t+3)&3 (safe: that buffer's reads
//   finished at the t-1 -> t barrier), ds_read frags from buf t&3, MFMA,
//   then s_waitcnt vmcnt(8) (allow tiles t+2,t+3 in flight; guarantee t+1
//   landed) + raw s_barrier. vmcnt never drains to 0 in steady state.
// BK=32 rows are 64 B, so each frag ds_read_b128 instruction's footprint
// spans full rows -> all 32 banks, 8 accesses/bank = HW minimum (no swizzle
// needed; the old [128][64] layout hit banks 0-15 only = 2x minimum).
// ---------------------------------------------------------------------------
__global__ __launch_bounds__(512, 2)
void gemm_bt256(const u16* __restrict__ A16, const u16* __restrict__ BT,
                u16* __restrict__ Cb, int M, int N, int K)
{
  __shared__ __align__(16) u16 As[4][256][32];
  __shared__ __align__(16) u16 Bs[4][256][32];
  const int tid  = threadIdx.x;
  const int wave = tid >> 6, lane = tid & 63;
  const int quad = lane >> 4, l16 = lane & 15;
  const int wm = wave >> 2, wn = wave & 3;   // 2 x 4 wave grid

  const int nb = N >> 8, mb = M >> 8;
  int band, nblk;
  if ((mb & 7) == 0) {
    int xcd = blockIdx.x & 7, slot = blockIdx.x >> 3;
    band = xcd + 8 * (slot / nb);
    nblk = slot % nb;
  } else {
    band = blockIdx.x / nb;
    nblk = blockIdx.x % nb;
  }
  const int m0 = band * 256, n0 = nblk * 256;
  const int nt = K >> 5;                     // BK=32 tiles

  // staging geometry: per tile 256 rows x 32 cols x 2B = 16 KiB per matrix
  // = 2 block-wide lds16 ops per matrix (512 lanes x 16 B = 8 KiB each).
  const int r0a = tid >> 2;                  // rows 0..127
  const int r1a = r0a + 128;                 // rows 128..255
  const int c8  = (tid & 3) << 3;            // col 0/8/16/24
  const int o0  = tid * 8;                   // u16 offset of this lane's 16 B
  const int o1  = o0 + 512 * 8;

  auto stage = [&](int t) {
    const int b = t & 3;
    const int k0 = t << 5;
    lds16(&A16[(size_t)(m0 + r0a) * K + k0 + c8], (u16*)As[b] + o0);
    lds16(&A16[(size_t)(m0 + r1a) * K + k0 + c8], (u16*)As[b] + o1);
    lds16(&BT [(size_t)(n0 + r0a) * K + k0 + c8], (u16*)Bs[b] + o0);
    lds16(&BT [(size_t)(n0 + r1a) * K + k0 + c8], (u16*)Bs[b] + o1);
  };

  f32x4 acc[8][4];
#pragma unroll
  for (int i = 0; i < 8; i++)
#pragma unroll
    for (int j = 0; j < 4; j++) acc[i][j] = f32x4{0.f, 0.f, 0.f, 0.f};

  // prologue: 3 tiles ahead; wait oldest tile (12 outstanding -> allow 8)
  stage(0); stage(1); stage(2);
  asm volatile("s_waitcnt vmcnt(8)" ::: "memory");
  __builtin_amdgcn_s_barrier();
  asm volatile("" ::: "memory");

  for (int t = 0; t < nt; ++t) {
    const int b = t & 3;
    if (t + 3 < nt) stage(t + 3);

    bf16x8 af[8], bf[4];
#pragma unroll
    for (int i = 0; i < 8; i++)
      af[i] = *(const bf16x8*)&As[b][wm * 128 + i * 16 + l16][quad * 8];
#pragma unroll
    for (int j = 0; j < 4; j++)
      bf[j] = *(const bf16x8*)&Bs[b][wn * 64 + j * 16 + l16][quad * 8];

    __builtin_amdgcn_s_setprio(1);
#pragma unroll
    for (int i = 0; i < 8; i++)
#pragma unroll
      for (int j = 0; j < 4; j++)
        acc[i][j] = __builtin_amdgcn_mfma_f32_16x16x32_bf16(af[i], bf[j], acc[i][j], 0, 0, 0);
    __builtin_amdgcn_s_setprio(0);

    if (t + 1 < nt) {
      // tiles issued beyond t+1 still allowed in flight
      const int last = (t + 3 < nt) ? (t + 3) : (nt - 1);
      const int pend = last - (t + 1);
      if (pend >= 2)      asm volatile("s_waitcnt vmcnt(8)" ::: "memory");
      else if (pend == 1) asm volatile("s_waitcnt vmcnt(4)" ::: "memory");
      else                asm volatile("s_waitcnt vmcnt(0)" ::: "memory");
      __builtin_amdgcn_s_barrier();
      asm volatile("" ::: "memory");
    }
  }

  // epilogue: C/D layout col=lane&15, row=quad*4+reg  (bf16 out, no bias)
#pragma unroll
  for (int i = 0; i < 8; i++) {
#pragma unroll
    for (int j = 0; j < 4; j++) {
      const int col = n0 + wn * 64 + j * 16 + l16;
#pragma unroll
      for (int r = 0; r < 4; r++) {
        const int row = m0 + wm * 128 + i * 16 + quad * 4 + r;
        Cb[(size_t)row * N + col] = f2bf(acc[i][j][r]);
      }
    }
  }
}

// ---------------------------------------------------------------------------
// Block-diagonal attention. Q pre-scaled by SCALE*log2e in the projection.
// No running max (scores bounded ~|4|: exp2 cannot overflow).
// S^T trick: mfma(kf, qf) gives P^T with 4 consecutive keys per lane ->
// pack via v_perm + single ds_write_b64 per tile. lsum indexed by l16.
// ---------------------------------------------------------------------------
__global__ __launch_bounds__(256)
void attn_kernel(const u16* __restrict__ qkv, u16* __restrict__ o)
{
  __shared__ u16 Ks[2][64][40];    // keys [key][d], 80B stride
  __shared__ u16 VTs[2][32][80];   // V^T [d][key], 160B stride
  __shared__ u16 Ps[4][32][72];    // per-wave P [qrow][key], 144B stride

  const int tid  = threadIdx.x;
  const int wave = tid >> 6, lane = tid & 63;
  const int quad = lane >> 4, l16 = lane & 15;
  const int qb    = blockIdx.x;        // 0..7
  const int head  = blockIdx.y >> 2;   // 0..7
  const int chunk = blockIdx.y & 3;    // 0..3
  const int b     = blockIdx.z;        // 0..3
  const size_t rowbase = (size_t)b * 4096 + chunk * 1024;
  const int tok0 = qb * 128 + wave * 32;

  bf16x8 qf[2];
#pragma unroll
  for (int qt = 0; qt < 2; qt++)
    qf[qt] = *(const bf16x8*)&qkv[(rowbase + tok0 + qt * 16 + l16) * 768 + head * 32 + quad * 8];

  float lsum[2] = {0.f, 0.f};
  f32x4 Oacc[2][2];
#pragma unroll
  for (int qt = 0; qt < 2; qt++)
#pragma unroll
    for (int nd = 0; nd < 2; nd++) Oacc[qt][nd] = f32x4{0.f, 0.f, 0.f, 0.f};

  const int sr = tid >> 2;           // key row 0..63
  const int sc = (tid & 3) << 3;     // d col 0,8,16,24
  const int rot = (sr + (sc >> 3)) & 7;

  {
    size_t base = (rowbase + sr) * 768 + head * 32;
    *(u16x8*)&Ks[0][sr][sc] = *(const u16x8*)&qkv[base + 256 + sc];
    u16x8 vv = *(const u16x8*)&qkv[base + 512 + sc];
#pragma unroll
    for (int jj = 0; jj < 8; jj++) {
      int j = (jj + rot) & 7;
      VTs[0][sc + j][sr] = vv[j];
    }
  }
  __syncthreads();

  for (int kb = 0; kb < 16; kb++) {
    int cur = kb & 1;

    u16x8 kreg, vreg;
    if (kb < 15) {
      size_t base = (rowbase + (kb + 1) * 64 + sr) * 768 + head * 32;
      kreg = *(const u16x8*)&qkv[base + 256 + sc];
      vreg = *(const u16x8*)&qkv[base + 512 + sc];
    }

    bf16x8 kf[4];
#pragma unroll
    for (int kt = 0; kt < 4; kt++)
      kf[kt] = *(const bf16x8*)&Ks[cur][kt * 16 + l16][quad * 8];

    f32x4 ST[4][2];
#pragma unroll
    for (int kt = 0; kt < 4; kt++)
#pragma unroll
      for (int qt = 0; qt < 2; qt++)
        ST[kt][qt] = __builtin_amdgcn_mfma_f32_16x16x32_bf16(kf[kt], qf[qt], f32x4{0.f,0.f,0.f,0.f}, 0, 0, 0);

#pragma unroll
    for (int qt = 0; qt < 2; qt++) {
#pragma unroll
      for (int kt = 0; kt < 4; kt++) {
        float p0 = exp2f(ST[kt][qt][0]);
        float p1 = exp2f(ST[kt][qt][1]);
        float p2 = exp2f(ST[kt][qt][2]);
        float p3 = exp2f(ST[kt][qt][3]);
        lsum[qt] += (p0 + p1) + (p2 + p3);
        u32 d0 = __builtin_amdgcn_perm(fbits(p1) + 0x8000u, fbits(p0) + 0x8000u, 0x07060302u);
        u32 d1 = __builtin_amdgcn_perm(fbits(p3) + 0x8000u, fbits(p2) + 0x8000u, 0x07060302u);
        uint2 dd; dd.x = d0; dd.y = d1;
        *(uint2*)&Ps[wave][qt * 16 + l16][kt * 16 + quad * 4] = dd;
      }
    }

#pragma unroll
    for (int ks = 0; ks < 2; ks++) {
      bf16x8 vf[2], pf[2];
#pragma unroll
      for (int nd = 0; nd < 2; nd++)
        vf[nd] = *(const bf16x8*)&VTs[cur][nd * 16 + l16][ks * 32 + quad * 8];
#pragma unroll
      for (int qt = 0; qt < 2; qt++)
        pf[qt] = *(const bf16x8*)&Ps[wave][qt * 16 + l16][ks * 32 + quad * 8];
#pragma unroll
      for (int qt = 0; qt < 2; qt++)
#pragma unroll
        for (int nd = 0; nd < 2; nd++)
          Oacc[qt][nd] = __builtin_amdgcn_mfma_f32_16x16x32_bf16(pf[qt], vf[nd], Oacc[qt][nd], 0, 0, 0);
    }

    if (kb < 15) {
      int nb = cur ^ 1;
      *(u16x8*)&Ks[nb][sr][sc] = kreg;
#pragma unroll
      for (int jj = 0; jj < 8; jj++) {
        int j = (jj + rot) & 7;
        VTs[nb][sc + j][sr] = vreg[j];
      }
    }
    __syncthreads();
  }

#pragma unroll
  for (int qt = 0; qt < 2; qt++) {
    float s = lsum[qt];
    s += __shfl_xor(s, 16);
    s += __shfl_xor(s, 32);
    lsum[qt] = s;
  }
#pragma unroll
  for (int qt = 0; qt < 2; qt++)
#pragma unroll
    for (int r = 0; r < 4; r++) {
      float inv = 1.0f / __shfl(lsum[qt], quad * 4 + r, 16);
      size_t row = rowbase + tok0 + qt * 16 + quad * 4 + r;
#pragma unroll
      for (int nd = 0; nd < 2; nd++) {
        int col = head * 32 + nd * 16 + l16;
        o[row * 256 + col] = f2bf(Oacc[qt][nd][r] * inv);
      }
    }
}

// ---------------------------------------------------------------------------
extern "C" void kernel_launch(void* const* d_in, const int* in_sizes, int n_in,
                              void* d_out, int out_size, void* d_ws, size_t ws_size,
                              hipStream_t stream)
{
  const float* x    = (const float*)d_in[0];
  const float* Wd   = (const float*)d_in[1];
  const float* Wqkv = (const float*)d_in[2];
  const float* Wup  = (const float*)d_in[3];
  const float* bup  = (const float*)d_in[4];
  float* out = (float*)d_out;

  const int M = 4 * 4096;  // 16384 tokens

  // workspace (u16 elems): WdC | WqkvT | WupT | WpT | qkv | ob | xb(optional)
  u16* WdC   = (u16*)d_ws;              // Wd cast      [1280][256]
  u16* WqkvT = WdC   + 1280 * 256;      // Wqkv^T       [768][256] (Q rows *CEXP)
  u16* WupT  = WqkvT + 768 * 256;      // Wup^T        [1280][256]
  u16* WpT   = WupT  + 1280 * 256;      // (Wd@Wqkv)^T  [768][1280]
  u16* qkv   = WpT   + 768 * 1280;      // [16384][768]
  u16* ob    = qkv   + (size_t)M * 768; // [16384][256]
  u16* xb    = ob    + (size_t)M * 256; // [16384][1280] bf16 cast of x

  const size_t need = ((size_t)(1280*256 + 768*256 + 1280*256 + 768*1280)
                       + (size_t)M * (768 + 256 + 1280)) * sizeof(u16);
  const bool use_xb = ws_size >= need;  // ws_size constant across calls

  const int n8 = use_xb ? (M * 1280 / 8) : 0;
  prep_all<<<(PREP_W + n8 + 255) / 256, 256, 0, stream>>>(
      Wd, Wqkv, Wup, x, WdC, WqkvT, WupT, xb, n8);

  // W'^T[n][k] = sum_c WqkvT[n][c] * Wd[k][c]  -> [768][1280] bf16
  gemm_bt<0><<<dim3((1280 / 128) * (768 / 128)), 256, 0, stream>>>(
      (const void*)WqkvT, WdC, WpT, nullptr, nullptr, 768, 1280, 256);

  if (use_xb) {
    // qkv = xb @ WpT^T : 256^2-tile counted-vmcnt pipeline
    gemm_bt256<<<dim3((768 / 256) * (M / 256)), 512, 0, stream>>>(
        xb, WpT, qkv, M, 768, 1280);
  } else {
    gemm_bt<1><<<dim3((768 / 128) * (M / 128)), 256, 0, stream>>>(
        (const void*)x, WpT, qkv, nullptr, nullptr, M, 768, 1280);
  }

  // block-diagonal attention
  attn_kernel<<<dim3(8, 32, 4), 256, 0, stream>>>(qkv, ob);

  // out = o @ Wup + bup (f32 out)
  gemm_bt<0><<<dim3((1280 / 128) * (M / 128)), 256, 0, stream>>>(
      (const void*)ob, WupT, nullptr, out, bup, M, 1280, 256);
}

// Round 2
// 298.435 us; speedup vs baseline: 1.0895x; 1.0489x over previous
//
#include <hip/hip_runtime.h>

typedef unsigned short u16;
typedef unsigned int u32;
typedef u16 u16x8 __attribute__((ext_vector_type(8)));
typedef __bf16 bf16x8 __attribute__((ext_vector_type(8)));
typedef float f32x4 __attribute__((ext_vector_type(4)));

__device__ __forceinline__ u16 f2bf(float f) {
  union { float f; unsigned u; } c; c.f = f;
  unsigned u = c.u;
  return (u16)((u + 0x7fff + ((u >> 16) & 1)) >> 16);
}

// fast exp2: scores are bounded (|S| ~ 4), raw v_exp_f32 is safe (1 ULP)
__device__ __forceinline__ float fexp2(float x) {
#if __has_builtin(__builtin_amdgcn_exp2f)
  return __builtin_amdgcn_exp2f(x);
#else
  float r; asm("v_exp_f32 %0, %1" : "=v"(r) : "v"(x)); return r;
#endif
}

// pack two f32 -> bf16x2 in one instruction (T12 recipe; no builtin on gfx950)
__device__ __forceinline__ u32 cvtpk(float lo, float hi) {
  u32 r;
  asm("v_cvt_pk_bf16_f32 %0, %1, %2" : "=v"(r) : "v"(lo), "v"(hi));
  return r;
}

// async global->LDS, 16B per lane. LDS dest must be wave-uniform base + lane*16.
__device__ __forceinline__ void lds16(const u16* g, u16* l) {
  __builtin_amdgcn_global_load_lds(
      (const __attribute__((address_space(1))) unsigned int*)g,
      (__attribute__((address_space(3))) unsigned int*)l, 16, 0, 0);
}

// SCALE = (1280//8)^-0.5, folded with log2(e); baked into Q-projection weights
#define CEXP (0.07905694150420949f * 1.4426950408889634f)

// ---------------------------------------------------------------------------
// combined prep: Wd cast | Wqkv^T (+CEXP on Q rows) | Wup^T | x -> bf16
// ---------------------------------------------------------------------------
#define PREP_W (1280 * 256 + 768 * 256 + 1280 * 256)   // 851968 weight elems

__global__ __launch_bounds__(256)
void prep_all(const float* __restrict__ Wd, const float* __restrict__ Wqkv,
              const float* __restrict__ Wup, const float* __restrict__ X,
              u16* __restrict__ WdC, u16* __restrict__ WqkvT,
              u16* __restrict__ WupT, u16* __restrict__ Xb, int n8) {
  int id = blockIdx.x * 256 + threadIdx.x;
  if (id < 1280 * 256) {                      // straight cast of Wd
    WdC[id] = f2bf(Wd[id]);
    return;
  }
  id -= 1280 * 256;
  if (id < 768 * 256) {                       // Wqkv^T, scale Q rows by CEXP
    int n = id >> 8, c = id & 255;
    float v = Wqkv[(size_t)c * 768 + n];
    if (n < 256) v *= CEXP;
    WqkvT[id] = f2bf(v);
    return;
  }
  id -= 768 * 256;
  if (id < 1280 * 256) {                      // Wup^T
    int n = id >> 8, c = id & 255;
    WupT[id] = f2bf(Wup[(size_t)c * 1280 + n]);
    return;
  }
  id -= 1280 * 256;
  if (id < n8) {                              // x -> bf16, 8 elems/thread
    const float4* src = (const float4*)(X + (size_t)id * 8);
    float4 lo = src[0], hi = src[1];
    u16x8 v;
    v[0]=f2bf(lo.x); v[1]=f2bf(lo.y); v[2]=f2bf(lo.z); v[3]=f2bf(lo.w);
    v[4]=f2bf(hi.x); v[5]=f2bf(hi.y); v[6]=f2bf(hi.z); v[7]=f2bf(hi.w);
    *(u16x8*)(Xb + (size_t)id * 8) = v;
  }
}

// ---------------------------------------------------------------------------
// GEMM: C[M,N] = A[M,K] * BT[N,K]^T (+bias). m97 structure: unpadded LDS,
// global_load_lds width=16. Kept for small/short-K GEMMs + AF32 fallback.
// 128x128 tile, 4 waves of 64x64, BK=64.
// ---------------------------------------------------------------------------
template <int AF32>
__global__ __launch_bounds__(256)
void gemm_bt(const void* __restrict__ Av,
             const u16* __restrict__ BT,
             u16* __restrict__ Cb, float* __restrict__ Cf,
             const float* __restrict__ bias,
             int M, int N, int K)
{
  __shared__ u16 As[128][64];
  __shared__ u16 Bs[128][64];
  const int tid  = threadIdx.x;
  const int wave = tid >> 6, lane = tid & 63;
  const int quad = lane >> 4, l16 = lane & 15;

  const int nb = N >> 7, mb = M >> 7;
  int band, nblk;
  if ((mb & 7) == 0) {
    int xcd = blockIdx.x & 7, slot = blockIdx.x >> 3;
    band = xcd + 8 * (slot / nb);
    nblk = slot % nb;
  } else {
    band = blockIdx.x / nb;
    nblk = blockIdx.x % nb;
  }
  const int m0 = band * 128, n0 = nblk * 128;
  const int wr = (wave >> 1) * 64, wc = (wave & 1) * 64;
  const u16*   A16 = (const u16*)Av;
  const float* A32 = (const float*)Av;

  f32x4 acc[4][4];
#pragma unroll
  for (int i = 0; i < 4; i++)
#pragma unroll
    for (int j = 0; j < 4; j++) acc[i][j] = f32x4{0.f, 0.f, 0.f, 0.f};

  for (int k0 = 0; k0 < K; k0 += 64) {
    if constexpr (AF32) {
#pragma unroll
      for (int it = 0; it < 4; it++) {
        int idx = tid + it * 256;
        int r = idx >> 3;
        int c = (idx & 7) << 3;
        const float* src = &A32[(size_t)(m0 + r) * K + k0 + c];
        float4 lo = *(const float4*)src;
        float4 hi = *(const float4*)(src + 4);
        u16x8 v;
        v[0]=f2bf(lo.x); v[1]=f2bf(lo.y); v[2]=f2bf(lo.z); v[3]=f2bf(lo.w);
        v[4]=f2bf(hi.x); v[5]=f2bf(hi.y); v[6]=f2bf(hi.z); v[7]=f2bf(hi.w);
        *(u16x8*)&As[r][c] = v;
      }
#pragma unroll
      for (int it = 0; it < 4; it++) {
        int r0 = wave * 32 + it * 8;
        lds16(&BT[(size_t)(n0 + r0 + (lane >> 3)) * K + k0 + ((lane & 7) << 3)],
              &Bs[r0][0] + lane * 8);
      }
    } else {
#pragma unroll
      for (int it = 0; it < 4; it++) {
        int r0 = wave * 32 + it * 8;
        lds16(&A16[(size_t)(m0 + r0 + (lane >> 3)) * K + k0 + ((lane & 7) << 3)],
              &As[r0][0] + lane * 8);
        lds16(&BT[(size_t)(n0 + r0 + (lane >> 3)) * K + k0 + ((lane & 7) << 3)],
              &Bs[r0][0] + lane * 8);
      }
    }
    __syncthreads();
#pragma unroll
    for (int ks = 0; ks < 64; ks += 32) {
      bf16x8 af[4], bfr[4];
#pragma unroll
      for (int i = 0; i < 4; i++)
        af[i] = *(const bf16x8*)&As[wr + i * 16 + l16][ks + quad * 8];
#pragma unroll
      for (int j = 0; j < 4; j++)
        bfr[j] = *(const bf16x8*)&Bs[wc + j * 16 + l16][ks + quad * 8];
#pragma unroll
      for (int i = 0; i < 4; i++)
#pragma unroll
        for (int j = 0; j < 4; j++)
          acc[i][j] = __builtin_amdgcn_mfma_f32_16x16x32_bf16(af[i], bfr[j], acc[i][j], 0, 0, 0);
    }
    __syncthreads();
  }

  // epilogue: C/D layout col=lane&15, row=quad*4+reg
#pragma unroll
  for (int i = 0; i < 4; i++) {
#pragma unroll
    for (int j = 0; j < 4; j++) {
      int col = n0 + wc + j * 16 + l16;
      float bv = bias ? bias[col] : 0.0f;
#pragma unroll
      for (int r = 0; r < 4; r++) {
        int row = m0 + wr + i * 16 + quad * 4 + r;
        float v = acc[i][j][r] + bv;
        if (Cf) Cf[(size_t)row * N + col] = v;
        else    Cb[(size_t)row * N + col] = f2bf(v);
      }
    }
  }
}

// ---------------------------------------------------------------------------
// Big-GEMM: 256x256 tile, 512 threads (8 waves 2Mx4N, wave tile 128x64),
// BK=32, 4 LDS buffers (128 KiB), counted-vmcnt pipeline (T3+T4).
// ---------------------------------------------------------------------------
__global__ __launch_bounds__(512, 2)
void gemm_bt256(const u16* __restrict__ A16, const u16* __restrict__ BT,
                u16* __restrict__ Cb, int M, int N, int K)
{
  __shared__ __align__(16) u16 As[4][256][32];
  __shared__ __align__(16) u16 Bs[4][256][32];
  const int tid  = threadIdx.x;
  const int wave = tid >> 6, lane = tid & 63;
  const int quad = lane >> 4, l16 = lane & 15;
  const int wm = wave >> 2, wn = wave & 3;   // 2 x 4 wave grid

  const int nb = N >> 8, mb = M >> 8;
  int band, nblk;
  if ((mb & 7) == 0) {
    int xcd = blockIdx.x & 7, slot = blockIdx.x >> 3;
    band = xcd + 8 * (slot / nb);
    nblk = slot % nb;
  } else {
    band = blockIdx.x / nb;
    nblk = blockIdx.x % nb;
  }
  const int m0 = band * 256, n0 = nblk * 256;
  const int nt = K >> 5;                     // BK=32 tiles

  const int r0a = tid >> 2;                  // rows 0..127
  const int r1a = r0a + 128;                 // rows 128..255
  const int c8  = (tid & 3) << 3;            // col 0/8/16/24
  const int o0  = tid * 8;                   // u16 offset of this lane's 16 B
  const int o1  = o0 + 512 * 8;

  auto stage = [&](int t) {
    const int b = t & 3;
    const int k0 = t << 5;
    lds16(&A16[(size_t)(m0 + r0a) * K + k0 + c8], (u16*)As[b] + o0);
    lds16(&A16[(size_t)(m0 + r1a) * K + k0 + c8], (u16*)As[b] + o1);
    lds16(&BT [(size_t)(n0 + r0a) * K + k0 + c8], (u16*)Bs[b] + o0);
    lds16(&BT [(size_t)(n0 + r1a) * K + k0 + c8], (u16*)Bs[b] + o1);
  };

  f32x4 acc[8][4];
#pragma unroll
  for (int i = 0; i < 8; i++)
#pragma unroll
    for (int j = 0; j < 4; j++) acc[i][j] = f32x4{0.f, 0.f, 0.f, 0.f};

  stage(0); stage(1); stage(2);
  asm volatile("s_waitcnt vmcnt(8)" ::: "memory");
  __builtin_amdgcn_s_barrier();
  asm volatile("" ::: "memory");

  for (int t = 0; t < nt; ++t) {
    const int b = t & 3;
    if (t + 3 < nt) stage(t + 3);

    bf16x8 af[8], bf[4];
#pragma unroll
    for (int i = 0; i < 8; i++)
      af[i] = *(const bf16x8*)&As[b][wm * 128 + i * 16 + l16][quad * 8];
#pragma unroll
    for (int j = 0; j < 4; j++)
      bf[j] = *(const bf16x8*)&Bs[b][wn * 64 + j * 16 + l16][quad * 8];

    __builtin_amdgcn_s_setprio(1);
#pragma unroll
    for (int i = 0; i < 8; i++)
#pragma unroll
      for (int j = 0; j < 4; j++)
        acc[i][j] = __builtin_amdgcn_mfma_f32_16x16x32_bf16(af[i], bf[j], acc[i][j], 0, 0, 0);
    __builtin_amdgcn_s_setprio(0);

    if (t + 1 < nt) {
      const int last = (t + 3 < nt) ? (t + 3) : (nt - 1);
      const int pend = last - (t + 1);
      if (pend >= 2)      asm volatile("s_waitcnt vmcnt(8)" ::: "memory");
      else if (pend == 1) asm volatile("s_waitcnt vmcnt(4)" ::: "memory");
      else                asm volatile("s_waitcnt vmcnt(0)" ::: "memory");
      __builtin_amdgcn_s_barrier();
      asm volatile("" ::: "memory");
    }
  }

#pragma unroll
  for (int i = 0; i < 8; i++) {
#pragma unroll
    for (int j = 0; j < 4; j++) {
      const int col = n0 + wn * 64 + j * 16 + l16;
#pragma unroll
      for (int r = 0; r < 4; r++) {
        const int row = m0 + wm * 128 + i * 16 + quad * 4 + r;
        Cb[(size_t)row * N + col] = f2bf(acc[i][j][r]);
      }
    }
  }
}

// ---------------------------------------------------------------------------
// One-shot V transpose: qkv V-third [token][d] -> vT[(b,chunk,head)][d=32][1024]
// Done ONCE here instead of per-(qb-block, kb) inside attention (8x redundant
// scatter removed from the attn hot loop; enables DMA staging of V there).
// ---------------------------------------------------------------------------
__global__ __launch_bounds__(256)
void vtrans(const u16* __restrict__ qkv, u16* __restrict__ vT)
{
  __shared__ u16 T[32][72];
  const int tid   = threadIdx.x;
  const int kt    = blockIdx.x;        // 0..15 : 64-token tile
  const int head  = blockIdx.y >> 2;   // 0..7
  const int chunk = blockIdx.y & 3;    // 0..3
  const int b     = blockIdx.z;        // 0..3
  const size_t rowbase = (size_t)b * 4096 + chunk * 1024 + kt * 64;

  const int tok = tid >> 2;            // 0..63
  const int d8  = (tid & 3) << 3;      // 0,8,16,24
  u16x8 vv = *(const u16x8*)&qkv[(rowbase + tok) * 768 + 512 + head * 32 + d8];
  const int rot = (tok + (d8 >> 3)) & 7;
#pragma unroll
  for (int jj = 0; jj < 8; jj++) {
    int j = (jj + rot) & 7;
    T[d8 + j][tok] = vv[j];
  }
  __syncthreads();
  const int d = tid >> 3;              // 0..31
  const int s = tid & 7;               // 8-key slot
  u16x8 out = *(const u16x8*)&T[d][s * 8];
  size_t obase = ((size_t)((b * 4 + chunk) * 8 + head)) * 32768
               + (size_t)d * 1024 + kt * 64 + s * 8;
  *(u16x8*)&vT[obase] = out;
}

// ---------------------------------------------------------------------------
// Block-diagonal attention. Q pre-scaled by SCALE*log2e in the projection.
// No running max (scores bounded ~|4|: exp2 cannot overflow).
// K and V^T staged via global_load_lds DMA (no register round-trip, no
// in-loop LDS writes). Ks rows are 64 B -> fragment reads conflict-free.
// VTs rows are 128 B -> content XOR-swizzled (slot' = slot ^ (d&7)) via the
// per-lane GLOBAL source address (LDS stays linear for the DMA); the same
// XOR is applied on the ds_read_b128 side -> conflict-free.
// Softmax: raw v_exp_f32 + v_cvt_pk_bf16_f32 packing (T12).
// ---------------------------------------------------------------------------
__global__ __launch_bounds__(256)
void attn_kernel(const u16* __restrict__ qkv, const u16* __restrict__ vT,
                 u16* __restrict__ o)
{
  __shared__ __align__(16) u16 Ks[2][64][32];    // keys [key][d]
  __shared__ __align__(16) u16 VTs[2][32][64];   // V^T  [d][key] (slot-swizzled)
  __shared__ u16 Ps[4][32][72];                  // per-wave P [qrow][key]

  const int tid  = threadIdx.x;
  const int wave = tid >> 6, lane = tid & 63;
  const int quad = lane >> 4, l16 = lane & 15;
  const int qb    = blockIdx.x;        // 0..7
  const int head  = blockIdx.y >> 2;   // 0..7
  const int chunk = blockIdx.y & 3;    // 0..3
  const int b     = blockIdx.z;        // 0..3
  const size_t rowbase = (size_t)b * 4096 + chunk * 1024;
  const int tok0 = qb * 128 + wave * 32;

  // staging lane maps (block-wide, 256 threads x 16 B = 4 KB per buffer)
  const int kkey = tid >> 2;                     // 0..63
  const int kd8  = (tid & 3) << 3;               // 0,8,16,24
  const int vr   = tid >> 3;                     // d row 0..31
  const int vs   = tid & 7;                      // LDS slot'
  const int vsl  = (vs ^ (vr & 7)) << 3;         // content key offset (XOR swz)
  const size_t vbase = ((size_t)((b * 4 + chunk) * 8 + head)) * 32768
                     + (size_t)vr * 1024 + vsl;

  auto stageKV = [&](int kb, int buf) {
    lds16(&qkv[(rowbase + kb * 64 + kkey) * 768 + 256 + head * 32 + kd8],
          &Ks[buf][0][0] + tid * 8);
    lds16(&vT[vbase + (size_t)kb * 64], &VTs[buf][0][0] + tid * 8);
  };

  stageKV(0, 0);

  bf16x8 qf[2];
#pragma unroll
  for (int qt = 0; qt < 2; qt++)
    qf[qt] = *(const bf16x8*)&qkv[(rowbase + tok0 + qt * 16 + l16) * 768 + head * 32 + quad * 8];

  float lsum[2] = {0.f, 0.f};
  f32x4 Oacc[2][2];
#pragma unroll
  for (int qt = 0; qt < 2; qt++)
#pragma unroll
    for (int nd = 0; nd < 2; nd++) Oacc[qt][nd] = f32x4{0.f, 0.f, 0.f, 0.f};

  __syncthreads();   // drains the DMA (vmcnt 0) + barrier

  for (int kb = 0; kb < 16; kb++) {
    const int cur = kb & 1;
    if (kb < 15) stageKV(kb + 1, cur ^ 1);

    bf16x8 kf[4];
#pragma unroll
    for (int kt = 0; kt < 4; kt++)
      kf[kt] = *(const bf16x8*)&Ks[cur][kt * 16 + l16][quad * 8];

    f32x4 ST[4][2];
    __builtin_amdgcn_s_setprio(1);
#pragma unroll
    for (int kt = 0; kt < 4; kt++)
#pragma unroll
      for (int qt = 0; qt < 2; qt++)
        ST[kt][qt] = __builtin_amdgcn_mfma_f32_16x16x32_bf16(kf[kt], qf[qt], f32x4{0.f,0.f,0.f,0.f}, 0, 0, 0);
    __builtin_amdgcn_s_setprio(0);

#pragma unroll
    for (int qt = 0; qt < 2; qt++) {
#pragma unroll
      for (int kt = 0; kt < 4; kt++) {
        float p0 = fexp2(ST[kt][qt][0]);
        float p1 = fexp2(ST[kt][qt][1]);
        float p2 = fexp2(ST[kt][qt][2]);
        float p3 = fexp2(ST[kt][qt][3]);
        lsum[qt] += (p0 + p1) + (p2 + p3);
        uint2 dd;
        dd.x = cvtpk(p0, p1);
        dd.y = cvtpk(p2, p3);
        *(uint2*)&Ps[wave][qt * 16 + l16][kt * 16 + quad * 4] = dd;
      }
    }

#pragma unroll
    for (int ks = 0; ks < 2; ks++) {
      bf16x8 vf[2], pf[2];
#pragma unroll
      for (int nd = 0; nd < 2; nd++)
        vf[nd] = *(const bf16x8*)&VTs[cur][nd * 16 + l16][((ks * 4 + quad) ^ (l16 & 7)) << 3];
#pragma unroll
      for (int qt = 0; qt < 2; qt++)
        pf[qt] = *(const bf16x8*)&Ps[wave][qt * 16 + l16][ks * 32 + quad * 8];
      __builtin_amdgcn_s_setprio(1);
#pragma unroll
      for (int qt = 0; qt < 2; qt++)
#pragma unroll
        for (int nd = 0; nd < 2; nd++)
          Oacc[qt][nd] = __builtin_amdgcn_mfma_f32_16x16x32_bf16(pf[qt], vf[nd], Oacc[qt][nd], 0, 0, 0);
      __builtin_amdgcn_s_setprio(0);
    }

    __syncthreads();   // drains this iteration's DMA + protects double buffer
  }

#pragma unroll
  for (int qt = 0; qt < 2; qt++) {
    float s = lsum[qt];
    s += __shfl_xor(s, 16);
    s += __shfl_xor(s, 32);
    lsum[qt] = s;
  }
#pragma unroll
  for (int qt = 0; qt < 2; qt++)
#pragma unroll
    for (int r = 0; r < 4; r++) {
      float inv = 1.0f / __shfl(lsum[qt], quad * 4 + r, 16);
      size_t row = rowbase + tok0 + qt * 16 + quad * 4 + r;
#pragma unroll
      for (int nd = 0; nd < 2; nd++) {
        int col = head * 32 + nd * 16 + l16;
        o[row * 256 + col] = f2bf(Oacc[qt][nd][r] * inv);
      }
    }
}

// ---------------------------------------------------------------------------
extern "C" void kernel_launch(void* const* d_in, const int* in_sizes, int n_in,
                              void* d_out, int out_size, void* d_ws, size_t ws_size,
                              hipStream_t stream)
{
  const float* x    = (const float*)d_in[0];
  const float* Wd   = (const float*)d_in[1];
  const float* Wqkv = (const float*)d_in[2];
  const float* Wup  = (const float*)d_in[3];
  const float* bup  = (const float*)d_in[4];
  float* out = (float*)d_out;

  const int M = 4 * 4096;  // 16384 tokens

  // workspace (u16 elems): WdC | WqkvT | WupT | WpT | qkv | ob | xb(optional)
  u16* WdC   = (u16*)d_ws;              // Wd cast      [1280][256]
  u16* WqkvT = WdC   + 1280 * 256;      // Wqkv^T       [768][256] (Q rows *CEXP)
  u16* WupT  = WqkvT + 768 * 256;       // Wup^T        [1280][256]
  u16* WpT   = WupT  + 1280 * 256;      // (Wd@Wqkv)^T  [768][1280]
  u16* qkv   = WpT   + 768 * 1280;      // [16384][768]
  u16* ob    = qkv   + (size_t)M * 768; // [16384][256]
  u16* xb    = ob    + (size_t)M * 256; // [16384][1280] bf16 cast of x
  // vT aliases xb: xb is dead after the qkv GEMM; vtrans runs after it.
  u16* vT    = xb;                      // [128][32][1024] V transposed

  const size_t need = ((size_t)(1280*256 + 768*256 + 1280*256 + 768*1280)
                       + (size_t)M * (768 + 256 + 1280)) * sizeof(u16);
  const bool use_xb = ws_size >= need;  // ws_size constant across calls

  const int n8 = use_xb ? (M * 1280 / 8) : 0;
  prep_all<<<(PREP_W + n8 + 255) / 256, 256, 0, stream>>>(
      Wd, Wqkv, Wup, x, WdC, WqkvT, WupT, xb, n8);

  // W'^T[n][k] = sum_c WqkvT[n][c] * Wd[k][c]  -> [768][1280] bf16
  gemm_bt<0><<<dim3((1280 / 128) * (768 / 128)), 256, 0, stream>>>(
      (const void*)WqkvT, WdC, WpT, nullptr, nullptr, 768, 1280, 256);

  if (use_xb) {
    gemm_bt256<<<dim3((768 / 256) * (M / 256)), 512, 0, stream>>>(
        xb, WpT, qkv, M, 768, 1280);
  } else {
    gemm_bt<1><<<dim3((768 / 128) * (M / 128)), 256, 0, stream>>>(
        (const void*)x, WpT, qkv, nullptr, nullptr, M, 768, 1280);
  }

  // one-shot V transpose (writes over the dead xb region)
  vtrans<<<dim3(16, 32, 4), 256, 0, stream>>>(qkv, vT);

  // block-diagonal attention
  attn_kernel<<<dim3(8, 32, 4), 256, 0, stream>>>(qkv, vT, ob);

  // out = o @ Wup + bup (f32 out)
  gemm_bt<0><<<dim3((1280 / 128) * (M / 128)), 256, 0, stream>>>(
      (const void*)ob, WupT, nullptr, out, bup, M, 1280, 256);
}

// Round 3
// 277.527 us; speedup vs baseline: 1.1716x; 1.0753x over previous
//
#include <hip/hip_runtime.h>

typedef unsigned short u16;
typedef unsigned int u32;
typedef u16 u16x8 __attribute__((ext_vector_type(8)));
typedef __bf16 bf16x8 __attribute__((ext_vector_type(8)));
typedef float f32x4 __attribute__((ext_vector_type(4)));

__device__ __forceinline__ u16 f2bf(float f) {
  union { float f; unsigned u; } c; c.f = f;
  unsigned u = c.u;
  return (u16)((u + 0x7fff + ((u >> 16) & 1)) >> 16);
}

// fast exp2: scores are bounded (|S| ~ 4), raw v_exp_f32 is safe (1 ULP)
__device__ __forceinline__ float fexp2(float x) {
  float r; asm("v_exp_f32 %0, %1" : "=v"(r) : "v"(x)); return r;
}

// pack two f32 -> bf16x2 in one instruction (T12 recipe; no builtin on gfx950)
__device__ __forceinline__ u32 cvtpk(float lo, float hi) {
  u32 r;
  asm("v_cvt_pk_bf16_f32 %0, %1, %2" : "=v"(r) : "v"(lo), "v"(hi));
  return r;
}

// async global->LDS, 16B per lane. LDS dest must be wave-uniform base + lane*16.
__device__ __forceinline__ void lds16(const u16* g, u16* l) {
  __builtin_amdgcn_global_load_lds(
      (const __attribute__((address_space(1))) unsigned int*)g,
      (__attribute__((address_space(3))) unsigned int*)l, 16, 0, 0);
}

// SCALE = (1280//8)^-0.5, folded with log2(e); baked into Q-projection weights
#define CEXP (0.07905694150420949f * 1.4426950408889634f)

// ---------------------------------------------------------------------------
// combined prep: Wd cast | Wqkv^T (+CEXP on Q rows) | Wup^T | x -> bf16
// ---------------------------------------------------------------------------
#define PREP_W (1280 * 256 + 768 * 256 + 1280 * 256)   // 851968 weight elems

__global__ __launch_bounds__(256)
void prep_all(const float* __restrict__ Wd, const float* __restrict__ Wqkv,
              const float* __restrict__ Wup, const float* __restrict__ X,
              u16* __restrict__ WdC, u16* __restrict__ WqkvT,
              u16* __restrict__ WupT, u16* __restrict__ Xb, int n8) {
  int id = blockIdx.x * 256 + threadIdx.x;
  if (id < 1280 * 256) {                      // straight cast of Wd
    WdC[id] = f2bf(Wd[id]);
    return;
  }
  id -= 1280 * 256;
  if (id < 768 * 256) {                       // Wqkv^T, scale Q rows by CEXP
    int n = id >> 8, c = id & 255;
    float v = Wqkv[(size_t)c * 768 + n];
    if (n < 256) v *= CEXP;
    WqkvT[id] = f2bf(v);
    return;
  }
  id -= 768 * 256;
  if (id < 1280 * 256) {                      // Wup^T
    int n = id >> 8, c = id & 255;
    WupT[id] = f2bf(Wup[(size_t)c * 1280 + n]);
    return;
  }
  id -= 1280 * 256;
  if (id < n8) {                              // x -> bf16, 8 elems/thread
    const float4* src = (const float4*)(X + (size_t)id * 8);
    float4 lo = src[0], hi = src[1];
    u16x8 v;
    v[0]=f2bf(lo.x); v[1]=f2bf(lo.y); v[2]=f2bf(lo.z); v[3]=f2bf(lo.w);
    v[4]=f2bf(hi.x); v[5]=f2bf(hi.y); v[6]=f2bf(hi.z); v[7]=f2bf(hi.w);
    *(u16x8*)(Xb + (size_t)id * 8) = v;
  }
}

// ---------------------------------------------------------------------------
// GEMM: C[M,N] = A[M,K] * BT[N,K]^T (+bias). m97 structure + content-XOR
// LDS swizzle (chunk^=row&7 on the 16B granule; both-sides involution, LDS
// stays linear for the DMA) -> fragment ds_read_b128 hits all 32 banks at
// the 8-access minimum. 128x128 tile, 4 waves of 64x64, BK=64.
// ---------------------------------------------------------------------------
template <int AF32>
__global__ __launch_bounds__(256)
void gemm_bt(const void* __restrict__ Av,
             const u16* __restrict__ BT,
             u16* __restrict__ Cb, float* __restrict__ Cf,
             const float* __restrict__ bias,
             int M, int N, int K)
{
  __shared__ u16 As[128][64];
  __shared__ u16 Bs[128][64];
  const int tid  = threadIdx.x;
  const int wave = tid >> 6, lane = tid & 63;
  const int quad = lane >> 4, l16 = lane & 15;
  const int rsw  = l16 & 7;                 // read-side row XOR
  const int ssw  = ((lane & 7) ^ (lane >> 3)) << 3;  // staging col (pre-swz)

  const int nb = N >> 7, mb = M >> 7;
  int band, nblk;
  if ((mb & 7) == 0) {
    int xcd = blockIdx.x & 7, slot = blockIdx.x >> 3;
    band = xcd + 8 * (slot / nb);
    nblk = slot % nb;
  } else {
    band = blockIdx.x / nb;
    nblk = blockIdx.x % nb;
  }
  const int m0 = band * 128, n0 = nblk * 128;
  const int wr = (wave >> 1) * 64, wc = (wave & 1) * 64;
  const u16*   A16 = (const u16*)Av;
  const float* A32 = (const float*)Av;

  f32x4 acc[4][4];
#pragma unroll
  for (int i = 0; i < 4; i++)
#pragma unroll
    for (int j = 0; j < 4; j++) acc[i][j] = f32x4{0.f, 0.f, 0.f, 0.f};

  for (int k0 = 0; k0 < K; k0 += 64) {
    if constexpr (AF32) {
#pragma unroll
      for (int it = 0; it < 4; it++) {
        int idx = tid + it * 256;
        int r = idx >> 3;
        const float* src = &A32[(size_t)(m0 + r) * K + k0 + ((idx & 7) << 3)];
        float4 lo = *(const float4*)src;
        float4 hi = *(const float4*)(src + 4);
        u16x8 v;
        v[0]=f2bf(lo.x); v[1]=f2bf(lo.y); v[2]=f2bf(lo.z); v[3]=f2bf(lo.w);
        v[4]=f2bf(hi.x); v[5]=f2bf(hi.y); v[6]=f2bf(hi.z); v[7]=f2bf(hi.w);
        *(u16x8*)&As[r][((idx & 7) ^ (r & 7)) << 3] = v;
      }
#pragma unroll
      for (int it = 0; it < 4; it++) {
        int r0 = wave * 32 + it * 8;
        lds16(&BT[(size_t)(n0 + r0 + (lane >> 3)) * K + k0 + ssw],
              &Bs[r0][0] + lane * 8);
      }
    } else {
#pragma unroll
      for (int it = 0; it < 4; it++) {
        int r0 = wave * 32 + it * 8;
        lds16(&A16[(size_t)(m0 + r0 + (lane >> 3)) * K + k0 + ssw],
              &As[r0][0] + lane * 8);
        lds16(&BT[(size_t)(n0 + r0 + (lane >> 3)) * K + k0 + ssw],
              &Bs[r0][0] + lane * 8);
      }
    }
    __syncthreads();
#pragma unroll
    for (int ks = 0; ks < 64; ks += 32) {
      bf16x8 af[4], bfr[4];
#pragma unroll
      for (int i = 0; i < 4; i++)
        af[i] = *(const bf16x8*)&As[wr + i * 16 + l16][(((ks >> 3) + quad) ^ rsw) << 3];
#pragma unroll
      for (int j = 0; j < 4; j++)
        bfr[j] = *(const bf16x8*)&Bs[wc + j * 16 + l16][(((ks >> 3) + quad) ^ rsw) << 3];
#pragma unroll
      for (int i = 0; i < 4; i++)
#pragma unroll
        for (int j = 0; j < 4; j++)
          acc[i][j] = __builtin_amdgcn_mfma_f32_16x16x32_bf16(af[i], bfr[j], acc[i][j], 0, 0, 0);
    }
    __syncthreads();
  }

  // epilogue: C/D layout col=lane&15, row=quad*4+reg
#pragma unroll
  for (int i = 0; i < 4; i++) {
#pragma unroll
    for (int j = 0; j < 4; j++) {
      int col = n0 + wc + j * 16 + l16;
      float bv = bias ? bias[col] : 0.0f;
#pragma unroll
      for (int r = 0; r < 4; r++) {
        int row = m0 + wr + i * 16 + quad * 4 + r;
        float v = acc[i][j][r] + bv;
        if (Cf) Cf[(size_t)row * N + col] = v;
        else    Cb[(size_t)row * N + col] = f2bf(v);
      }
    }
  }
}

// ---------------------------------------------------------------------------
// Big-GEMM, 8-phase schedule (T2+T3+T4+T5 port of the m201 template):
// 256x256 tile, 512 threads (8 waves 2Mx4N, wave tile 128x64), BK=64,
// 2 dbuf x 2 half-slots per matrix (128 KiB LDS). Per iteration = 2 K-tiles
// = 8 phases of {ds_read subtile | stage 1 half-slot | barrier | setprio(1)
// 16 MFMA setprio(0) | barrier}. Counted vmcnt(2) at phases 4/8 only (the
// newest half-slot stays in flight across every wait; vmcnt(0) only at the
// tail). Stage targets follow slot deadness: A-slots die after P3/P7,
// B-slots after P4/P8 -> every DMA overwrite is behind a barrier that
// retired all reads of that slot. LDS content-XOR (chunk^=row&7, applied on
// the pre-swizzled global source + the ds_read side) -> conflict-free.
// ---------------------------------------------------------------------------
#define BAR()  do { asm volatile("" ::: "memory"); \
                    __builtin_amdgcn_s_barrier(); \
                    asm volatile("" ::: "memory"); } while (0)
#define VMC(n) asm volatile("s_waitcnt vmcnt(" #n ")" ::: "memory")

#define LDA_(d, ib) { _Pragma("unroll") for (int i = 0; i < 4; i++) \
  _Pragma("unroll") for (int ks = 0; ks < 2; ks++) \
    af[i*2+ks] = *(const bf16x8*)&As[d][wm][(ib+i)*16 + l16][((ks*4+quad) ^ rsw) << 3]; }

#define LDB_(d, dst, jp) { _Pragma("unroll") for (int j = 0; j < 2; j++) \
  _Pragma("unroll") for (int ks = 0; ks < 2; ks++) \
    dst[j*2+ks] = *(const bf16x8*)&Bs[d][bh][br + (jp*2+j)*16 + l16][((ks*4+quad) ^ rsw) << 3]; }

#define MM_(ib, jp, breg) { __builtin_amdgcn_s_setprio(1); \
  _Pragma("unroll") for (int i = 0; i < 4; i++) \
  _Pragma("unroll") for (int j = 0; j < 2; j++) \
  _Pragma("unroll") for (int ks = 0; ks < 2; ks++) \
    acc[ib+i][jp*2+j] = __builtin_amdgcn_mfma_f32_16x16x32_bf16( \
        af[i*2+ks], breg[j*2+ks], acc[ib+i][jp*2+j], 0, 0, 0); \
  __builtin_amdgcn_s_setprio(0); }

__global__ __launch_bounds__(512, 2)
void gemm_bt256(const u16* __restrict__ A16, const u16* __restrict__ BT,
                u16* __restrict__ Cb, int M, int N, int K)
{
  __shared__ __align__(16) u16 As[2][2][128][64];  // [dbuf][half][row][col]
  __shared__ __align__(16) u16 Bs[2][2][128][64];
  const int tid  = threadIdx.x;
  const int wave = tid >> 6, lane = tid & 63;
  const int quad = lane >> 4, l16 = lane & 15;
  const int wm = wave >> 2, wn = wave & 3;   // 2 x 4 wave grid
  const int bh = wn >> 1, br = (wn & 1) * 64;
  const int rsw = l16 & 7;

  const int nb = N >> 8, mb = M >> 8;
  int band, nblk;
  if ((mb & 7) == 0) {
    int xcd = blockIdx.x & 7, slot = blockIdx.x >> 3;
    band = xcd + 8 * (slot / nb);
    nblk = slot % nb;
  } else {
    band = blockIdx.x / nb;
    nblk = blockIdx.x % nb;
  }
  const int m0 = band * 256, n0 = nblk * 256;
  const int NT = K >> 6;                     // 64-wide K tiles (even, >=4)

  // staging: one half-slot (128 rows x 64 cols) = 2 block-wide lds16 ops.
  const int srow = tid >> 3;                 // 0..63
  const int scol = ((tid & 7) ^ (srow & 7)) << 3;  // pre-swizzled global col

  auto stageA = [&](int t, int h) {
    const int d = t & 1;
    const size_t g = (size_t)(m0 + h * 128 + srow) * K + (t << 6) + scol;
    lds16(&A16[g], &As[d][h][0][0] + tid * 8);
    lds16(&A16[g + (size_t)64 * K], &As[d][h][64][0] + tid * 8);
  };
  auto stageB = [&](int t, int h) {
    const int d = t & 1;
    const size_t g = (size_t)(n0 + h * 128 + srow) * K + (t << 6) + scol;
    lds16(&BT[g], &Bs[d][h][0][0] + tid * 8);
    lds16(&BT[g + (size_t)64 * K], &Bs[d][h][64][0] + tid * 8);
  };

  bf16x8 af[8], b0[4], b1[4];
  f32x4 acc[8][4];
#pragma unroll
  for (int i = 0; i < 8; i++)
#pragma unroll
    for (int j = 0; j < 4; j++) acc[i][j] = f32x4{0.f, 0.f, 0.f, 0.f};

  // prologue: tile0 complete + tile1 A-half0
  stageA(0, 0); stageA(0, 1); stageB(0, 0); stageB(0, 1); stageA(1, 0);
  VMC(2);
  BAR();

  const int nIter = NT >> 1;
  for (int it = 0; it < nIter; ++it) {
    const int t0 = it * 2, t1 = t0 + 1;
    const bool more  = (t0 + 2 < NT);
    const bool more1 = (t1 + 2 < NT);

    // ---- dbuf0 (tile t0) ----
    // P1: A i0-3 + B j0-1; stage A1[1] of t1
    LDA_(0, 0); LDB_(0, b0, 0);
    stageA(t1, 1);
    BAR(); MM_(0, 0, b0); BAR();
    // P2: B j2-3; stage B1[0] of t1
    LDB_(0, b1, 1);
    stageB(t1, 0);
    BAR(); MM_(0, 1, b1); BAR();
    // P3: A i4-7; stage B1[1] of t1
    LDA_(0, 4);
    stageB(t1, 1);
    BAR(); MM_(4, 1, b1); BAR();
    // P4: no reads; stage A0[0] of t0+2; counted wait for dbuf1 readiness
    if (more) stageA(t0 + 2, 0);
    BAR(); MM_(4, 0, b0);
    if (more) { VMC(2); } else { VMC(0); }
    BAR();

    // ---- dbuf1 (tile t1) ----
    // P5
    LDA_(1, 0); LDB_(1, b0, 0);
    if (more) stageA(t0 + 2, 1);
    BAR(); MM_(0, 0, b0); BAR();
    // P6
    LDB_(1, b1, 1);
    if (more) stageB(t0 + 2, 0);
    BAR(); MM_(0, 1, b1); BAR();
    // P7
    LDA_(1, 4);
    if (more) stageB(t0 + 2, 1);
    BAR(); MM_(4, 1, b1); BAR();
    // P8
    if (more1) stageA(t1 + 2, 0);
    BAR(); MM_(4, 0, b0);
    if (it + 1 < nIter) {
      if (more1) { VMC(2); } else { VMC(0); }
      BAR();
    }
  }

  // epilogue: C/D layout col=lane&15, row=quad*4+reg  (bf16 out, no bias)
#pragma unroll
  for (int i = 0; i < 8; i++) {
#pragma unroll
    for (int j = 0; j < 4; j++) {
      const int col = n0 + wn * 64 + j * 16 + l16;
#pragma unroll
      for (int r = 0; r < 4; r++) {
        const int row = m0 + wm * 128 + i * 16 + quad * 4 + r;
        Cb[(size_t)row * N + col] = f2bf(acc[i][j][r]);
      }
    }
  }
}

// ---------------------------------------------------------------------------
// One-shot V transpose: qkv V-third [token][d] -> vT[(b,chunk,head)][d=32][1024]
// ---------------------------------------------------------------------------
__global__ __launch_bounds__(256)
void vtrans(const u16* __restrict__ qkv, u16* __restrict__ vT)
{
  __shared__ u16 T[32][72];
  const int tid   = threadIdx.x;
  const int kt    = blockIdx.x;        // 0..15 : 64-token tile
  const int head  = blockIdx.y >> 2;   // 0..7
  const int chunk = blockIdx.y & 3;    // 0..3
  const int b     = blockIdx.z;        // 0..3
  const size_t rowbase = (size_t)b * 4096 + chunk * 1024 + kt * 64;

  const int tok = tid >> 2;            // 0..63
  const int d8  = (tid & 3) << 3;      // 0,8,16,24
  u16x8 vv = *(const u16x8*)&qkv[(rowbase + tok) * 768 + 512 + head * 32 + d8];
  const int rot = (tok + (d8 >> 3)) & 7;
#pragma unroll
  for (int jj = 0; jj < 8; jj++) {
    int j = (jj + rot) & 7;
    T[d8 + j][tok] = vv[j];
  }
  __syncthreads();
  const int d = tid >> 3;              // 0..31
  const int s = tid & 7;               // 8-key slot
  u16x8 out = *(const u16x8*)&T[d][s * 8];
  size_t obase = ((size_t)((b * 4 + chunk) * 8 + head)) * 32768
               + (size_t)d * 1024 + kt * 64 + s * 8;
  *(u16x8*)&vT[obase] = out;
}

// ---------------------------------------------------------------------------
// Block-diagonal attention. Q pre-scaled by SCALE*log2e in the projection.
// K and V^T staged via global_load_lds DMA; VTs content XOR-swizzled via the
// per-lane global source address. Softmax: raw v_exp_f32 + cvt_pk packing.
// ---------------------------------------------------------------------------
__global__ __launch_bounds__(256)
void attn_kernel(const u16* __restrict__ qkv, const u16* __restrict__ vT,
                 u16* __restrict__ o)
{
  __shared__ __align__(16) u16 Ks[2][64][32];    // keys [key][d]
  __shared__ __align__(16) u16 VTs[2][32][64];   // V^T  [d][key] (slot-swizzled)
  __shared__ u16 Ps[4][32][72];                  // per-wave P [qrow][key]

  const int tid  = threadIdx.x;
  const int wave = tid >> 6, lane = tid & 63;
  const int quad = lane >> 4, l16 = lane & 15;
  const int qb    = blockIdx.x;        // 0..7
  const int head  = blockIdx.y >> 2;   // 0..7
  const int chunk = blockIdx.y & 3;    // 0..3
  const int b     = blockIdx.z;        // 0..3
  const size_t rowbase = (size_t)b * 4096 + chunk * 1024;
  const int tok0 = qb * 128 + wave * 32;

  const int kkey = tid >> 2;                     // 0..63
  const int kd8  = (tid & 3) << 3;               // 0,8,16,24
  const int vr   = tid >> 3;                     // d row 0..31
  const int vs   = tid & 7;                      // LDS slot'
  const int vsl  = (vs ^ (vr & 7)) << 3;         // content key offset (XOR swz)
  const size_t vbase = ((size_t)((b * 4 + chunk) * 8 + head)) * 32768
                     + (size_t)vr * 1024 + vsl;

  auto stageKV = [&](int kb, int buf) {
    lds16(&qkv[(rowbase + kb * 64 + kkey) * 768 + 256 + head * 32 + kd8],
          &Ks[buf][0][0] + tid * 8);
    lds16(&vT[vbase + (size_t)kb * 64], &VTs[buf][0][0] + tid * 8);
  };

  stageKV(0, 0);

  bf16x8 qf[2];
#pragma unroll
  for (int qt = 0; qt < 2; qt++)
    qf[qt] = *(const bf16x8*)&qkv[(rowbase + tok0 + qt * 16 + l16) * 768 + head * 32 + quad * 8];

  float lsum[2] = {0.f, 0.f};
  f32x4 Oacc[2][2];
#pragma unroll
  for (int qt = 0; qt < 2; qt++)
#pragma unroll
    for (int nd = 0; nd < 2; nd++) Oacc[qt][nd] = f32x4{0.f, 0.f, 0.f, 0.f};

  __syncthreads();   // drains the DMA (vmcnt 0) + barrier

  for (int kb = 0; kb < 16; kb++) {
    const int cur = kb & 1;
    if (kb < 15) stageKV(kb + 1, cur ^ 1);

    bf16x8 kf[4];
#pragma unroll
    for (int kt = 0; kt < 4; kt++)
      kf[kt] = *(const bf16x8*)&Ks[cur][kt * 16 + l16][quad * 8];

    f32x4 ST[4][2];
    __builtin_amdgcn_s_setprio(1);
#pragma unroll
    for (int kt = 0; kt < 4; kt++)
#pragma unroll
      for (int qt = 0; qt < 2; qt++)
        ST[kt][qt] = __builtin_amdgcn_mfma_f32_16x16x32_bf16(kf[kt], qf[qt], f32x4{0.f,0.f,0.f,0.f}, 0, 0, 0);
    __builtin_amdgcn_s_setprio(0);

#pragma unroll
    for (int qt = 0; qt < 2; qt++) {
#pragma unroll
      for (int kt = 0; kt < 4; kt++) {
        float p0 = fexp2(ST[kt][qt][0]);
        float p1 = fexp2(ST[kt][qt][1]);
        float p2 = fexp2(ST[kt][qt][2]);
        float p3 = fexp2(ST[kt][qt][3]);
        lsum[qt] += (p0 + p1) + (p2 + p3);
        uint2 dd;
        dd.x = cvtpk(p0, p1);
        dd.y = cvtpk(p2, p3);
        *(uint2*)&Ps[wave][qt * 16 + l16][kt * 16 + quad * 4] = dd;
      }
    }

#pragma unroll
    for (int ks = 0; ks < 2; ks++) {
      bf16x8 vf[2], pf[2];
#pragma unroll
      for (int nd = 0; nd < 2; nd++)
        vf[nd] = *(const bf16x8*)&VTs[cur][nd * 16 + l16][((ks * 4 + quad) ^ (l16 & 7)) << 3];
#pragma unroll
      for (int qt = 0; qt < 2; qt++)
        pf[qt] = *(const bf16x8*)&Ps[wave][qt * 16 + l16][ks * 32 + quad * 8];
      __builtin_amdgcn_s_setprio(1);
#pragma unroll
      for (int qt = 0; qt < 2; qt++)
#pragma unroll
        for (int nd = 0; nd < 2; nd++)
          Oacc[qt][nd] = __builtin_amdgcn_mfma_f32_16x16x32_bf16(pf[qt], vf[nd], Oacc[qt][nd], 0, 0, 0);
      __builtin_amdgcn_s_setprio(0);
    }

    __syncthreads();   // drains this iteration's DMA + protects double buffer
  }

#pragma unroll
  for (int qt = 0; qt < 2; qt++) {
    float s = lsum[qt];
    s += __shfl_xor(s, 16);
    s += __shfl_xor(s, 32);
    lsum[qt] = s;
  }
#pragma unroll
  for (int qt = 0; qt < 2; qt++)
#pragma unroll
    for (int r = 0; r < 4; r++) {
      float inv = 1.0f / __shfl(lsum[qt], quad * 4 + r, 16);
      size_t row = rowbase + tok0 + qt * 16 + quad * 4 + r;
#pragma unroll
      for (int nd = 0; nd < 2; nd++) {
        int col = head * 32 + nd * 16 + l16;
        o[row * 256 + col] = f2bf(Oacc[qt][nd][r] * inv);
      }
    }
}

// ---------------------------------------------------------------------------
extern "C" void kernel_launch(void* const* d_in, const int* in_sizes, int n_in,
                              void* d_out, int out_size, void* d_ws, size_t ws_size,
                              hipStream_t stream)
{
  const float* x    = (const float*)d_in[0];
  const float* Wd   = (const float*)d_in[1];
  const float* Wqkv = (const float*)d_in[2];
  const float* Wup  = (const float*)d_in[3];
  const float* bup  = (const float*)d_in[4];
  float* out = (float*)d_out;

  const int M = 4 * 4096;  // 16384 tokens

  // workspace (u16 elems): WdC | WqkvT | WupT | WpT | qkv | ob | xb(optional)
  u16* WdC   = (u16*)d_ws;              // Wd cast      [1280][256]
  u16* WqkvT = WdC   + 1280 * 256;      // Wqkv^T       [768][256] (Q rows *CEXP)
  u16* WupT  = WqkvT + 768 * 256;       // Wup^T        [1280][256]
  u16* WpT   = WupT  + 1280 * 256;      // (Wd@Wqkv)^T  [768][1280]
  u16* qkv   = WpT   + 768 * 1280;      // [16384][768]
  u16* ob    = qkv   + (size_t)M * 768; // [16384][256]
  u16* xb    = ob    + (size_t)M * 256; // [16384][1280] bf16 cast of x
  // vT aliases xb: xb is dead after the qkv GEMM; vtrans runs after it.
  u16* vT    = xb;                      // [128][32][1024] V transposed

  const size_t need = ((size_t)(1280*256 + 768*256 + 1280*256 + 768*1280)
                       + (size_t)M * (768 + 256 + 1280)) * sizeof(u16);
  const bool use_xb = ws_size >= need;  // ws_size constant across calls

  const int n8 = use_xb ? (M * 1280 / 8) : 0;
  prep_all<<<(PREP_W + n8 + 255) / 256, 256, 0, stream>>>(
      Wd, Wqkv, Wup, x, WdC, WqkvT, WupT, xb, n8);

  // W'^T[n][k] = sum_c WqkvT[n][c] * Wd[k][c]  -> [768][1280] bf16
  gemm_bt<0><<<dim3((1280 / 128) * (768 / 128)), 256, 0, stream>>>(
      (const void*)WqkvT, WdC, WpT, nullptr, nullptr, 768, 1280, 256);

  if (use_xb) {
    gemm_bt256<<<dim3((768 / 256) * (M / 256)), 512, 0, stream>>>(
        xb, WpT, qkv, M, 768, 1280);
  } else {
    gemm_bt<1><<<dim3((768 / 128) * (M / 128)), 256, 0, stream>>>(
        (const void*)x, WpT, qkv, nullptr, nullptr, M, 768, 1280);
  }

  // one-shot V transpose (writes over the dead xb region)
  vtrans<<<dim3(16, 32, 4), 256, 0, stream>>>(qkv, vT);

  // block-diagonal attention
  attn_kernel<<<dim3(8, 32, 4), 256, 0, stream>>>(qkv, vT, ob);

  // out = o @ Wup + bup (f32 out)
  gemm_bt<0><<<dim3((1280 / 128) * (M / 128)), 256, 0, stream>>>(
      (const void*)ob, WupT, nullptr, out, bup, M, 1280, 256);
}